// Round 9
// baseline (2604.091 us; speedup 1.0000x reference)
//
#include <hip/hip_runtime.h>

// Problem constants (reference: B=32, S=8192, D=32, C=256)
#define S_LEN 8192
#define BATCH 32
#define DH    32
#define NC    256
#define NCHUNK (S_LEN / 64)

typedef float f32x2 __attribute__((ext_vector_type(2)));

// DPP controls (gfx9 encoding): row_ror:N = 0x120|N, row = 16 lanes.
#define ROR1 0x121
#define ROR2 0x122
#define ROR4 0x124
#define ROR8 0x128

#if defined(__has_builtin)
#if __has_builtin(__builtin_amdgcn_permlane16_swap)
#define HAS_PL16 1
#else
#define HAS_PL16 0
#endif
#else
#define HAS_PL16 0
#endif

__device__ __forceinline__ float rdlane(float v, int l) {
    return __int_as_float(__builtin_amdgcn_readlane(__float_as_int(v), l));
}
__device__ __forceinline__ float bperm(int byte_addr, float v) {
    return __int_as_float(__builtin_amdgcn_ds_bpermute(byte_addr, __float_as_int(v)));
}
template <int CTRL>
__device__ __forceinline__ float dppf(float v) {
    return __int_as_float(__builtin_amdgcn_update_dpp(
        0, __float_as_int(v), CTRL, 0xF, 0xF, false));
}

struct FPair { float odd_b, even_b; };
#if HAS_PL16
// permlane16_swap with equal inputs: one result = odd-16-row value broadcast
// to both rows of the pair, the other = even-16-row value. SEL (probed) says
// which index is the odd-row broadcast. Returned BY VALUE: a non-const
// reference cannot bind to an ext_vector element (r8 compile failure).
template <int SEL>
__device__ __forceinline__ FPair pl16(float v) {
    auto r = __builtin_amdgcn_permlane16_swap(
        __float_as_uint(v), __float_as_uint(v), false, false);
    FPair p;
    p.odd_b  = __uint_as_float(r[SEL]);
    p.even_b = __uint_as_float(r[SEL ^ 1]);
    return p;
}
#endif

template <int M> struct IC { static constexpr int value = M; };

// One wave per batch. Lane j owns gate columns k1=j (i|f) and k2=j+64 (g|o);
// h replicated in both half-waves. r7 post-mortem: LDS h-broadcast put a
// ~150-cyc ds_write->ds_read round trip on the 8192-step serial chain.
// This round: all-VALU butterfly broadcast (15 DPP row_ror + 16
// permlane16_swap, chain depth 5) producing packed f32x2 h-pairs; weight
// columns are loaded PRE-PERMUTED per lane using runtime-probed shuffle
// offsets, so any HW rotation direction / result order is correct.
__global__ __launch_bounds__(64, 1) __attribute__((amdgpu_waves_per_eu(1, 1)))
void lstm_scan_kernel(
    const float* __restrict__ x,      // (B,S)
    const float* __restrict__ bos,    // (D)
    const float* __restrict__ W_in,   // (1,D)
    const float* __restrict__ b_in,   // (D)
    const float* __restrict__ Wx,     // (D,4D)
    const float* __restrict__ Wh,     // (D,4D)
    const float* __restrict__ b_lstm, // (4D)
    float* __restrict__ hs)           // (B,S,D) workspace
{
    __shared__ __align__(16) float hl[DH];   // used by LDS fallback path only

    const int b    = blockIdx.x;
    const int lane = threadIdx.x;     // 0..63
    const int col  = lane & 31;
    const int r15  = lane & 15;
    const int k1   = lane;
    const int k2   = lane + 64;
    const bool lo  = lane < 32;
    const int swap_addr = (lane ^ 32) << 2;

    // Packed cubic coefficients: .x sigmoid (i|f); .y tanh (g) on lo lanes,
    // sigmoid (o) on hi lanes. |z| <= ~0.05 -> cubic error < 5e-8.
    f32x2 Cq, Cl, Cc;
    Cq.x = -1.f/48.f; Cq.y = lo ? -1.f/3.f : -1.f/48.f;
    Cl.x = 0.25f;     Cl.y = lo ? 1.f      : 0.25f;
    Cc.x = 0.5f;      Cc.y = lo ? 0.f      : 0.5f;

    // Rank-1 input projection constants:
    //   zx[t,k] = x[t-1]*v_k + u_k  (t>=1),  zx[0,k] = z0_k
    float u1 = b_lstm[k1], u2 = b_lstm[k2];
    float z01 = u1, z02 = u2;         // bos @ Wx + b_lstm (bos used raw)
    float v1 = 0.f, v2 = 0.f;
#pragma unroll
    for (int d = 0; d < DH; ++d) {
        const float wx1 = Wx[d * 4 * DH + k1];
        const float wx2 = Wx[d * 4 * DH + k2];
        const float wi = W_in[d];
        v1 = fmaf(wi, wx1, v1);  v2 = fmaf(wi, wx2, v2);
        const float bi = b_in[d];
        u1 = fmaf(bi, wx1, u1);  u2 = fmaf(bi, wx2, u2);
        const float bd = bos[d];
        z01 = fmaf(bd, wx1, z01); z02 = fmaf(bd, wx2, z02);
    }

    const float* xb = x + (size_t)b * S_LEN;

    // ---- runtime probes (wave-uniform, once) ----
    // permlane32_swap direction (gate exchange):
    const unsigned li = (unsigned)lane;
    auto pr = __builtin_amdgcn_permlane32_swap(li, li, false, false);
    const unsigned pa = __builtin_amdgcn_readfirstlane(pr[0]);
    const unsigned pb = __builtin_amdgcn_readfirstlane(pr[1]);
    int pm;
    if (pa == 32u && pb == 0u)      pm = 0;
    else if (pa == 0u && pb == 32u) pm = 1;
    else                            pm = 2;

    // DPP row_ror offsets (direction-agnostic: we only need the actual
    // source-offset each control implements; lane 0's received lane-id IS it).
    const int lif = lane;
    const int o1 = __builtin_amdgcn_readfirstlane(
        __builtin_amdgcn_update_dpp(0, lif, ROR1, 0xF, 0xF, false)) & 15;
    const int o2 = __builtin_amdgcn_readfirstlane(
        __builtin_amdgcn_update_dpp(0, lif, ROR2, 0xF, 0xF, false)) & 15;
    const int o4 = __builtin_amdgcn_readfirstlane(
        __builtin_amdgcn_update_dpp(0, lif, ROR4, 0xF, 0xF, false)) & 15;
    const int o8 = __builtin_amdgcn_readfirstlane(
        __builtin_amdgcn_update_dpp(0, lif, ROR8, 0xF, 0xF, false)) & 15;

    // permlane16_swap result order (which result is the odd-row broadcast):
    int bm = 2;
#if HAS_PL16
    {
        auto q = __builtin_amdgcn_permlane16_swap(li, li, false, false);
        const unsigned qa = __builtin_amdgcn_readfirstlane(q[0]);
        const unsigned qb = __builtin_amdgcn_readfirstlane(q[1]);
        if (qa == 16u)      bm = 0;   // r[0] = odd-row bcast
        else if (qb == 16u) bm = 1;   // r[1] = odd-row bcast
        else                bm = 2;   // unknown -> LDS fallback
    }
#endif

    auto run = [&](auto mode_tag, auto b_tag) {
        constexpr int MODE = decltype(mode_tag)::value;
        constexpr int B    = decltype(b_tag)::value;

        // ---- weights, layout per path ----
        f32x2 w1U[8], w1V[8], w2U[8], w2V[8];   // butterfly (pre-permuted)
        f32x2 wh1p[16], wh2p[16];               // LDS path (linear pairs)
        if constexpr (B == 2) {
#pragma unroll
            for (int dd = 0; dd < 16; ++dd) {
                wh1p[dd].x = Wh[(2*dd    ) * 4 * DH + k1];
                wh1p[dd].y = Wh[(2*dd + 1) * 4 * DH + k1];
                wh2p[dd].x = Wh[(2*dd    ) * 4 * DH + k2];
                wh2p[dd].y = Wh[(2*dd + 1) * 4 * DH + k2];
            }
        } else {
            // Pair m element e holds h[d] with within-16 offset
            // (r15 + O(m) + e*o1) & 15; O(m) = b0*o2 + b1*o4 + b2*o8.
            // U = d|16 (odd 16-group), V = d (even 16-group). Subset-sum
            // bijectivity holds for any probed signs of o1/o2/o4/o8.
#pragma unroll
            for (int m = 0; m < 8; ++m) {
                const int O = ((m & 1) ? o2 : 0) + ((m & 2) ? o4 : 0)
                            + ((m & 4) ? o8 : 0);
                const int d0 = (r15 + O) & 15;
                const int d1 = (r15 + O + o1) & 15;
                w1U[m].x = Wh[(16 | d0) * 4 * DH + k1];
                w1U[m].y = Wh[(16 | d1) * 4 * DH + k1];
                w1V[m].x = Wh[d0 * 4 * DH + k1];
                w1V[m].y = Wh[d1 * 4 * DH + k1];
                w2U[m].x = Wh[(16 | d0) * 4 * DH + k2];
                w2U[m].y = Wh[(16 | d1) * 4 * DH + k2];
                w2V[m].x = Wh[d0 * 4 * DH + k2];
                w2V[m].y = Wh[d1 * 4 * DH + k2];
            }
        }

        float* hp = hs + (size_t)b * S_LEN * DH + col;
        float c = 0.f, h = 0.f;

        auto exch = [&](float v, float& hi_b, float& lo_b) {
            if constexpr (MODE == 2) {
                const float p = bperm(swap_addr, v);
                hi_b = lo ? p : v;
                lo_b = lo ? v : p;
            } else {
                auto r = __builtin_amdgcn_permlane32_swap(
                    __float_as_uint(v), __float_as_uint(v), false, false);
                if constexpr (MODE == 0) { hi_b = __uint_as_float(r[0]); lo_b = __uint_as_float(r[1]); }
                else                     { hi_b = __uint_as_float(r[1]); lo_b = __uint_as_float(r[0]); }
            }
        };

        auto gates = [&](float z1, float z2) {
            f32x2 zp; zp.x = z1; zp.y = z2;
            const f32x2 t_ = zp * zp;
            const f32x2 r_ = t_ * Cq + Cl;
            const f32x2 s_ = zp * r_ + Cc;
            float f_, i_, o_, g_;
            exch(s_.x, f_, i_);   // f_=sig(f), i_=sig(i) in all lanes
            exch(s_.y, o_, g_);   // o_=sig(o), g_=tanh(g) in all lanes
            c = fmaf(f_, c, i_ * g_);
            const float tt_ = c * c;
            const float tc_ = c * fmaf(tt_, -(1.f/3.f), 1.f);  // tanh(c) cubic
            h = o_ * tc_;
            if constexpr (B == 2) hl[col] = h;   // LDS path broadcast stage
            *hp = h; hp += DH;
        };

        // step 0 peeled: z from the bos projection
        gates(z01, z02);

        // lane holds x[t-1] for t = chunk*64 + lane
        float xc = (lane >= 1) ? xb[lane - 1] : 0.f;

        for (int chunk = 0; chunk < NCHUNK; ++chunk) {
            // In-loop pins: force weight residency across the serial loop
            // (r6 lesson: out-of-loop pin lets LICM sink reloads back in).
            if constexpr (B == 2) {
                asm volatile("" : "+v"(wh1p[0]), "+v"(wh1p[1]), "+v"(wh1p[2]), "+v"(wh1p[3]),
                                 "+v"(wh1p[4]), "+v"(wh1p[5]), "+v"(wh1p[6]), "+v"(wh1p[7]));
                asm volatile("" : "+v"(wh1p[8]), "+v"(wh1p[9]), "+v"(wh1p[10]), "+v"(wh1p[11]),
                                 "+v"(wh1p[12]), "+v"(wh1p[13]), "+v"(wh1p[14]), "+v"(wh1p[15]));
                asm volatile("" : "+v"(wh2p[0]), "+v"(wh2p[1]), "+v"(wh2p[2]), "+v"(wh2p[3]),
                                 "+v"(wh2p[4]), "+v"(wh2p[5]), "+v"(wh2p[6]), "+v"(wh2p[7]));
                asm volatile("" : "+v"(wh2p[8]), "+v"(wh2p[9]), "+v"(wh2p[10]), "+v"(wh2p[11]),
                                 "+v"(wh2p[12]), "+v"(wh2p[13]), "+v"(wh2p[14]), "+v"(wh2p[15]));
            } else {
                asm volatile("" : "+v"(w1U[0]), "+v"(w1U[1]), "+v"(w1U[2]), "+v"(w1U[3]),
                                 "+v"(w1U[4]), "+v"(w1U[5]), "+v"(w1U[6]), "+v"(w1U[7]));
                asm volatile("" : "+v"(w1V[0]), "+v"(w1V[1]), "+v"(w1V[2]), "+v"(w1V[3]),
                                 "+v"(w1V[4]), "+v"(w1V[5]), "+v"(w1V[6]), "+v"(w1V[7]));
                asm volatile("" : "+v"(w2U[0]), "+v"(w2U[1]), "+v"(w2U[2]), "+v"(w2U[3]),
                                 "+v"(w2U[4]), "+v"(w2U[5]), "+v"(w2U[6]), "+v"(w2U[7]));
                asm volatile("" : "+v"(w2V[0]), "+v"(w2V[1]), "+v"(w2V[2]), "+v"(w2V[3]),
                                 "+v"(w2V[4]), "+v"(w2V[5]), "+v"(w2V[6]), "+v"(w2V[7]));
            }
            asm volatile("" : "+v"(u1), "+v"(u2), "+v"(v1), "+v"(v2),
                             "+v"(Cq), "+v"(Cl), "+v"(Cc));

            float xn = 0.f;
            if (chunk + 1 < NCHUNK) xn = xb[(chunk + 1) * 64 - 1 + lane];

#pragma unroll 2
            for (int i = (chunk == 0) ? 1 : 0; i < 64; ++i) {
                const float xs = rdlane(xc, i);
                const float zx1 = fmaf(xs, v1, u1);
                const float zx2 = fmaf(xs, v2, u2);
                float z1, z2;

                if constexpr (B == 2) {
                    // LDS broadcast path (r7): 8 uniform-address b128 reads.
                    float4 hq[8];
#pragma unroll
                    for (int q = 0; q < 8; ++q)
                        hq[q] = *(const float4*)&hl[4 * q];
                    f32x2 a1, b1_, a2, b2_;
                    a1 = 0.f; b1_ = 0.f; a2 = 0.f; b2_ = 0.f;
#pragma unroll
                    for (int q = 0; q < 8; ++q) {
                        f32x2 l2, h2;
                        l2.x = hq[q].x; l2.y = hq[q].y;
                        h2.x = hq[q].z; h2.y = hq[q].w;
                        a1 += l2 * wh1p[2*q];  b1_ += h2 * wh1p[2*q + 1];
                        a2 += l2 * wh2p[2*q];  b2_ += h2 * wh2p[2*q + 1];
                    }
                    const f32x2 s1 = a1 + b1_;
                    const f32x2 s2 = a2 + b2_;
                    z1 = zx1 + (s1.x + s1.y);
                    z2 = zx2 + (s2.x + s2.y);
                }
#if HAS_PL16
                else {
                    // VALU butterfly broadcast: depth-5 chain, no LDS.
                    f32x2 P[8];
                    P[0].x = h;
                    P[0].y = dppf<ROR1>(h);
                    P[1].x = dppf<ROR2>(P[0].x); P[1].y = dppf<ROR2>(P[0].y);
                    P[2].x = dppf<ROR4>(P[0].x); P[2].y = dppf<ROR4>(P[0].y);
                    P[3].x = dppf<ROR4>(P[1].x); P[3].y = dppf<ROR4>(P[1].y);
                    P[4].x = dppf<ROR8>(P[0].x); P[4].y = dppf<ROR8>(P[0].y);
                    P[5].x = dppf<ROR8>(P[1].x); P[5].y = dppf<ROR8>(P[1].y);
                    P[6].x = dppf<ROR8>(P[2].x); P[6].y = dppf<ROR8>(P[2].y);
                    P[7].x = dppf<ROR8>(P[3].x); P[7].y = dppf<ROR8>(P[3].y);
                    f32x2 U[8], V[8];
#pragma unroll
                    for (int m = 0; m < 8; ++m) {
                        const FPair px = pl16<B>(P[m].x);
                        U[m].x = px.odd_b;  V[m].x = px.even_b;
                        const FPair py = pl16<B>(P[m].y);
                        U[m].y = py.odd_b;  V[m].y = py.even_b;
                    }
                    f32x2 a1 = U[0] * w1U[0];
                    f32x2 b1_ = U[1] * w1U[1];
                    f32x2 c1 = U[2] * w1U[2];
                    f32x2 d1 = U[3] * w1U[3];
                    a1 += U[4] * w1U[4]; b1_ += U[5] * w1U[5];
                    c1 += U[6] * w1U[6]; d1 += U[7] * w1U[7];
                    a1 += V[0] * w1V[0]; b1_ += V[1] * w1V[1];
                    c1 += V[2] * w1V[2]; d1 += V[3] * w1V[3];
                    a1 += V[4] * w1V[4]; b1_ += V[5] * w1V[5];
                    c1 += V[6] * w1V[6]; d1 += V[7] * w1V[7];
                    const f32x2 s1 = (a1 + b1_) + (c1 + d1);
                    z1 = zx1 + (s1.x + s1.y);

                    f32x2 a2 = U[0] * w2U[0];
                    f32x2 b2_ = U[1] * w2U[1];
                    f32x2 c2 = U[2] * w2U[2];
                    f32x2 d2 = U[3] * w2U[3];
                    a2 += U[4] * w2U[4]; b2_ += U[5] * w2U[5];
                    c2 += U[6] * w2U[6]; d2 += U[7] * w2U[7];
                    a2 += V[0] * w2V[0]; b2_ += V[1] * w2V[1];
                    c2 += V[2] * w2V[2]; d2 += V[3] * w2V[3];
                    a2 += V[4] * w2V[4]; b2_ += V[5] * w2V[5];
                    c2 += V[6] * w2V[6]; d2 += V[7] * w2V[7];
                    const f32x2 s2 = (a2 + b2_) + (c2 + d2);
                    z2 = zx2 + (s2.x + s2.y);
                }
#else
                else { z1 = zx1; z2 = zx2; }   // never instantiated
#endif
                gates(z1, z2);
            }
            xc = xn;
        }
    };

    if (bm == 0) {
        if (pm == 0)      run(IC<0>{}, IC<0>{});
        else if (pm == 1) run(IC<1>{}, IC<0>{});
        else              run(IC<2>{}, IC<0>{});
    } else if (bm == 1) {
        if (pm == 0)      run(IC<0>{}, IC<1>{});
        else if (pm == 1) run(IC<1>{}, IC<1>{});
        else              run(IC<2>{}, IC<1>{});
    } else {
        if (pm == 0)      run(IC<0>{}, IC<2>{});
        else if (pm == 1) run(IC<1>{}, IC<2>{});
        else              run(IC<2>{}, IC<2>{});
    }
}

// Projection: logits[b,t,c] = hs[b,t,:] @ W_out[:,c] + b_out[c]
// (unchanged, verified)
__global__ __launch_bounds__(256, 4) void proj_kernel(
    const float* __restrict__ hs,     // (B,S,D)
    const float* __restrict__ W_out,  // (D,C)
    const float* __restrict__ b_out,  // (C)
    float* __restrict__ out)          // (B,S,C)
{
    __shared__ float hbuf[128 * DH];  // 16 KiB
    const int tid = threadIdx.x;
    const int b   = blockIdx.y;
    const int t0  = blockIdx.x * 128;

    const float4* src4 = (const float4*)(hs + ((size_t)b * S_LEN + t0) * DH);
    float4* dst4 = (float4*)hbuf;
#pragma unroll
    for (int k = 0; k < 4; ++k) dst4[tid + k * 256] = src4[tid + k * 256];
    __syncthreads();

    const int cc = tid;               // output column
    f32x2 w2[16];
#pragma unroll
    for (int d = 0; d < 16; ++d) {
        w2[d].x = W_out[(2*d    ) * NC + cc];
        w2[d].y = W_out[(2*d + 1) * NC + cc];
    }
    const float bo = b_out[cc];

    float* dst = out + ((size_t)b * S_LEN + t0) * NC + cc;
#pragma unroll 2
    for (int r = 0; r < 128; ++r) {
        const float4* row4 = (const float4*)(hbuf + r * DH);
        f32x2 acc_a; acc_a.x = 0.f; acc_a.y = 0.f;
        f32x2 acc_b; acc_b.x = 0.f; acc_b.y = 0.f;
#pragma unroll
        for (int q = 0; q < 8; ++q) {
            const float4 hv = row4[q];
            f32x2 h01; h01.x = hv.x; h01.y = hv.y;
            f32x2 h23; h23.x = hv.z; h23.y = hv.w;
            acc_a += h01 * w2[2*q];
            acc_b += h23 * w2[2*q + 1];
        }
        const f32x2 s = acc_a + acc_b;
        dst[(size_t)r * NC] = (bo + s.x) + s.y;
    }
}

extern "C" void kernel_launch(void* const* d_in, const int* in_sizes, int n_in,
                              void* d_out, int out_size, void* d_ws, size_t ws_size,
                              hipStream_t stream) {
    const float* x      = (const float*)d_in[0];
    const float* bos    = (const float*)d_in[1];
    const float* W_in   = (const float*)d_in[2];
    const float* b_in   = (const float*)d_in[3];
    const float* Wx     = (const float*)d_in[4];
    const float* Wh     = (const float*)d_in[5];
    const float* b_lstm = (const float*)d_in[6];
    const float* W_out  = (const float*)d_in[7];
    const float* b_out  = (const float*)d_in[8];

    float* out = (float*)d_out;
    float* hs  = (float*)d_ws;   // needs B*S*D*4 = 33.5 MB of workspace

    lstm_scan_kernel<<<dim3(BATCH), dim3(64), 0, stream>>>(
        x, bos, W_in, b_in, Wx, Wh, b_lstm, hs);
    proj_kernel<<<dim3(S_LEN / 128, BATCH), dim3(256), 0, stream>>>(
        hs, W_out, b_out, out);
}